// Round 5
// baseline (944.830 us; speedup 1.0000x reference)
//
#include <hip/hip_runtime.h>
#include <hip/hip_bf16.h>
#include <cstdint>
#include <cstddef>

#define H 512
#define NFEAT 1024
#define BATCH 16384

using bf16 = __hip_bfloat16;
using bf16x8 = __attribute__((ext_vector_type(8))) __bf16;
using f32x4 = __attribute__((ext_vector_type(4))) float;
using f32x16 = __attribute__((ext_vector_type(16))) float;

// ---------------------------------------------------------------------------
// async global -> LDS, 16 bytes per lane
// ---------------------------------------------------------------------------
__device__ __forceinline__ void gload16(void* lds, const void* g) {
  __builtin_amdgcn_global_load_lds(
      (__attribute__((address_space(1))) void*)g,
      (__attribute__((address_space(3))) void*)lds,
      16, 0, 0);
}

// ---------------------------------------------------------------------------
// prep: per matrix, compute a[], b[] for core = diag(d) + a*1^T + b*u^T
// Closed-form Cayley (rank-2 Woodbury), verified R0-R4.
// ---------------------------------------------------------------------------
__global__ void prep_kernel(const float* __restrict__ er, const float* __restrict__ ed,
                            const float* __restrict__ dr, const float* __restrict__ dd,
                            float* __restrict__ ab) {
  const int mat = blockIdx.x;          // 0..7
  const int lane = threadIdx.x;        // 0..63
  const float* u = (mat < 4) ? (er + mat * H) : (dr + (mat - 4) * H);
  const float* d = (mat < 4) ? (ed + mat * H) : (dd + (mat - 4) * H);

  double s = 0.0, q = 0.0;
  for (int k = 0; k < 8; ++k) {
    double v = (double)u[lane + 64 * k];
    s += v;
    q += v * v;
  }
  for (int off = 32; off; off >>= 1) {
    s += __shfl_down(s, off);
    q += __shfl_down(q, off);
  }
  s = __shfl(s, 0);
  q = __shfl(q, 0);

  const double det = 1.0 - s * s + (double)H * q;
  const double cuv = 2.0 * (1.0 + s) / det;
  const double cuu = -2.0 * (double)H / det;
  const double cvv = -2.0 * q / det;
  const double cvu = -2.0 * (1.0 - s) / det;

  float* a = ab + mat * 1024;
  float* b = a + H;
  for (int k = 0; k < 8; ++k) {
    int idx = lane + 64 * k;
    double ui = (double)u[idx], di = (double)d[idx];
    a[idx] = (float)(di * (cuv * ui + cvv));
    b[idx] = (float)(di * (cuu * ui + cvu));
  }
}

// ---------------------------------------------------------------------------
// prep2: stride-4-residue inclusive prefix tables over a, a_rev, d, d_rev.
// ---------------------------------------------------------------------------
__global__ __launch_bounds__(256) void prep2_kernel(
    const float* __restrict__ er, const float* __restrict__ ed,
    const float* __restrict__ dr, const float* __restrict__ dd,
    const float* __restrict__ ab, float* __restrict__ Tpref) {
  __shared__ float buf[4][512];
  __shared__ float tmp[4][512];
  const int mat = blockIdx.x;
  const float* d = (mat < 4) ? (ed + mat * H) : (dd + (mat - 4) * H);
  const float* a = ab + mat * 1024;
  const int t = threadIdx.x;
  for (int m = t; m < 512; m += 256) {
    buf[0][m] = a[m];
    buf[1][m] = a[511 - m];
    buf[2][m] = d[m];
    buf[3][m] = d[511 - m];
  }
  __syncthreads();
  for (int s = 4; s <= 256; s <<= 1) {
    for (int m = t; m < 512; m += 256)
#pragma unroll
      for (int q = 0; q < 4; ++q) tmp[q][m] = (m >= s) ? buf[q][m - s] : 0.f;
    __syncthreads();
    for (int m = t; m < 512; m += 256)
#pragma unroll
      for (int q = 0; q < 4; ++q) buf[q][m] += tmp[q][m];
    __syncthreads();
  }
  float* tp = Tpref + mat * 2048;
  for (int m = t; m < 512; m += 256) {
    tp[m] = buf[0][m];
    tp[512 + m] = buf[1][m];
    tp[1024 + m] = buf[2][m];
    tp[1536 + m] = buf[3][m];
  }
}

// ---------------------------------------------------------------------------
// build v3 (unchanged from R2): prefix tables + quad b*u loop.
// ---------------------------------------------------------------------------
__global__ __launch_bounds__(256) void build_kernel(
    const float* __restrict__ er, const float* __restrict__ ed,
    const float* __restrict__ dr, const float* __restrict__ dd,
    const float* __restrict__ ab, const float* __restrict__ Tpref,
    bf16* __restrict__ Lh, bf16* __restrict__ Ll) {
  __shared__ __align__(16) float arr4[4][520];
  __shared__ __align__(16) float4 up[132];
  __shared__ float pa[512], parev[512], pd[512], pdrev[512], sdl[512];

  const int i = blockIdx.x;
  const int mat = blockIdx.y;
  const float* u = (mat < 4) ? (er + mat * H) : (dr + (mat - 4) * H);
  const float* d = (mat < 4) ? (ed + mat * H) : (dd + (mat - 4) * H);
  const float* a = ab + mat * 1024;
  const float* b = a + H;
  const float* tp = Tpref + mat * 2048;
  const int t = threadIdx.x;

  for (int m = t; m < 520; m += 256) {
    arr4[0][m] = (m < 512) ? u[m] : 0.f;
    arr4[1][m] = (m >= 1 && m <= 512) ? b[m - 1] : 0.f;
    arr4[2][m] = (m >= 2 && m <= 513) ? u[513 - m] : 0.f;
    arr4[3][m] = (m >= 3 && m <= 514) ? b[514 - m] : 0.f;
  }
  for (int m = t; m < 512; m += 256) {
    pa[m] = tp[m];
    parev[m] = tp[512 + m];
    pd[m] = tp[1024 + m];
    pdrev[m] = tp[1536 + m];
    sdl[m] = d[m];
  }
  if (t < 132) {
    const int k4 = 4 * t;
    float4 v;
    int p0 = i - k4;
    v.x = (p0 >= 0 && p0 < 512) ? b[p0] : 0.f;
    int p1 = i - k4 - 1;
    v.y = (p1 >= 0 && p1 < 512) ? u[511 - p1] : 0.f;
    int p2 = i - k4 - 2;
    v.z = (p2 >= 0 && p2 < 512) ? b[511 - p2] : 0.f;
    int p3 = i - k4 - 3;
    v.w = (p3 >= 0 && p3 < 512) ? u[p3] : 0.f;
    up[t] = v;
  }
  __syncthreads();

  const float* upf = (const float*)up;
  const int j0 = t * 4;

  int lo_[4], hi_[4];
#pragma unroll
  for (int c = 0; c < 4; ++c) {
    const int jc = j0 + c;
    lo_[c] = max(0, max(i, jc) - 511);
    hi_[c] = min(512, min(i, jc));
  }
  const int CL = lo_[3];
  const int CH = hi_[0];

  float acc[4] = {0.f, 0.f, 0.f, 0.f};

#pragma unroll
  for (int c = 0; c < 4; ++c) {
    const int jc = j0 + c;
    const int lo = lo_[c], hi = hi_[c];
    if (lo > hi) continue;
    float v = 0.f;
    {
      int o1 = lo + ((0 - lo) & 3), o2 = hi - ((hi - 0) & 3);
      if (o1 <= o2) { int mx = i - o1, mn = i - o2; v += pa[mx] - (mn >= 4 ? pa[mn - 4] : 0.f); }
    }
    {
      int o1 = lo + ((1 - lo) & 3), o2 = hi - ((hi - 1) & 3);
      if (o1 <= o2) { int mx = jc - o1, mn = jc - o2; v += pa[mx] - (mn >= 4 ? pa[mn - 4] : 0.f); }
    }
    {
      int o1 = lo + ((2 - lo) & 3), o2 = hi - ((hi - 2) & 3);
      if (o1 <= o2) { int mx = i - o1, mn = i - o2; v += parev[mx] - (mn >= 4 ? parev[mn - 4] : 0.f); }
    }
    {
      int o1 = lo + ((3 - lo) & 3), o2 = hi - ((hi - 3) & 3);
      if (o1 <= o2) { int mx = jc - o1, mn = jc - o2; v += parev[mx] - (mn >= 4 ? parev[mn - 4] : 0.f); }
    }
    if (i == jc) {
      {
        int o1 = lo + ((0 - lo) & 3), o2 = hi - ((hi - 0) & 3);
        if (o1 <= o2) { int mx = i - o1, mn = i - o2; v += pd[mx] - (mn >= 4 ? pd[mn - 4] : 0.f); }
      }
      {
        int o1 = lo + ((2 - lo) & 3), o2 = hi - ((hi - 2) & 3);
        if (o1 <= o2) { int mx = i - o1, mn = i - o2; v += pdrev[mx] - (mn >= 4 ? pdrev[mn - 4] : 0.f); }
      }
    }
    const int m2 = i + jc - 511;
    if (m2 >= 0 && !(m2 & 1)) {
      const int os = m2 >> 1;
      if (os >= lo && os <= hi) {
        const int r = os & 3;
        if (r == 1) v += sdl[jc - os];
        else if (r == 3) v += sdl[511 - (jc - os)];
      }
    }
    acc[c] = v;
  }

  if (CL > CH) {
#pragma unroll
    for (int c = 0; c < 4; ++c) {
      const int jc = j0 + c;
      for (int o = lo_[c]; o <= hi_[c]; ++o) {
        const int r = o & 3;
        acc[c] += upf[o] * arr4[r][jc - o + r];
      }
    }
  } else {
#pragma unroll
    for (int c = 0; c < 4; ++c) {
      const int jc = j0 + c;
      const int he = min(hi_[c], CL - 1);
      for (int o = lo_[c]; o <= he; ++o) {
        const int r = o & 3;
        acc[c] += upf[o] * arr4[r][jc - o + r];
      }
      const int ls = max(lo_[c], CH + 1);
      for (int o = ls; o <= hi_[c]; ++o) {
        const int r = o & 3;
        acc[c] += upf[o] * arr4[r][jc - o + r];
      }
    }
    const int QL = (CL + 3) & ~3;
    for (int o = CL; o < QL && o <= CH; ++o) {
      const int r = o & 3;
      const float uvv = upf[o];
      const float4 wv = *(const float4*)&arr4[r][j0 - o + r];
      acc[0] += uvv * wv.x; acc[1] += uvv * wv.y;
      acc[2] += uvv * wv.z; acc[3] += uvv * wv.w;
    }
    int ob = QL;
    for (; ob + 3 <= CH; ob += 4) {
      const float4 uv = up[ob >> 2];
      const int x = j0 - ob;
      const float4 w0 = *(const float4*)&arr4[0][x];
      const float4 w1 = *(const float4*)&arr4[1][x];
      const float4 w2 = *(const float4*)&arr4[2][x];
      const float4 w3 = *(const float4*)&arr4[3][x];
      acc[0] += uv.x * w0.x + uv.y * w1.x + uv.z * w2.x + uv.w * w3.x;
      acc[1] += uv.x * w0.y + uv.y * w1.y + uv.z * w2.y + uv.w * w3.y;
      acc[2] += uv.x * w0.z + uv.y * w1.z + uv.z * w2.z + uv.w * w3.z;
      acc[3] += uv.x * w0.w + uv.y * w1.w + uv.z * w2.w + uv.w * w3.w;
    }
    for (int o = ob; o <= CH; ++o) {
      const int r = o & 3;
      const float uvv = upf[o];
      const float4 wv = *(const float4*)&arr4[r][j0 - o + r];
      acc[0] += uvv * wv.x; acc[1] += uvv * wv.y;
      acc[2] += uvv * wv.z; acc[3] += uvv * wv.w;
    }
  }

  const size_t off = ((size_t)mat << 20) + ((size_t)i << 10) + (size_t)j0;
  union { bf16 v[4]; ushort4 s; } Hu, Lu;
#pragma unroll
  for (int c = 0; c < 4; ++c) {
    const bf16 hb = __float2bfloat16(acc[c]);
    Hu.v[c] = hb;
    Lu.v[c] = __float2bfloat16(acc[c] - __bfloat162float(hb));
  }
  *(ushort4*)(Lh + off) = Hu.s;
  *(ushort4*)(Ll + off) = Lu.s;
}

// ---------------------------------------------------------------------------
// split fp32 -> (hi, lo) bf16
// ---------------------------------------------------------------------------
__global__ void split_kernel(const float* __restrict__ x, bf16* __restrict__ h,
                             bf16* __restrict__ l) {
  const int n4 = BATCH * NFEAT / 4;
  int idx = blockIdx.x * blockDim.x + threadIdx.x;
  int stride = gridDim.x * blockDim.x;
  for (int i = idx; i < n4; i += stride) {
    float4 v = ((const float4*)x)[i];
    float vv[4] = {v.x, v.y, v.z, v.w};
    union { bf16 b[4]; short4 s; } Hu, Lu;
#pragma unroll
    for (int c = 0; c < 4; ++c) {
      bf16 hb = __float2bfloat16(vv[c]);
      Hu.b[c] = hb;
      Lu.b[c] = __float2bfloat16(vv[c] - __bfloat162float(hb));
    }
    ((short4*)h)[i] = Hu.s;
    ((short4*)l)[i] = Lu.s;
  }
}

// ---------------------------------------------------------------------------
// split-bf16 GEMM v3:  Y[r][c] = sum_k S[r][k] * L[c][k]  (Y = S @ L^T)
// acc += Ah*Bh + Ah*Bl + Al*Bh (fp32 accum).
// 256x256 tile, BK=16, 8 waves (2Mx4N, wave-out 128x64), mfma_f32_32x32x16.
// Double-buffered LDS (2 x 32KB), issue-early staging, counted vmcnt(4)
// (never 0 in main loop), raw s_barrier + explicit lgkmcnt(0), setprio(1)
// around the MFMA cluster.
// LDS per array [256 rows][16 k] bf16 (32-B rows); swizzle: 16B-slot index
// XORed with (row>>2)&1, applied on BOTH stage source and frag read.
// MODE bit0: write fp32 Yf; bit1: write split (Yh, Yl)
// ---------------------------------------------------------------------------
template <int MODE>
__global__ __launch_bounds__(512, 2) void gemm3_kernel(
    const bf16* __restrict__ Ah, const bf16* __restrict__ Al,
    const bf16* __restrict__ Bh, const bf16* __restrict__ Bl,
    float* __restrict__ Yf, bf16* __restrict__ Yh, bf16* __restrict__ Yl) {
  // 2 buffers x 4 arrays x 4096 elems (8KB): Ah | Al | Bh | Bl
  __shared__ __align__(16) bf16 smem[2 * 4 * 4096];  // 64 KiB

  const int tid = threadIdx.x;   // 0..511
  const int lane = tid & 63;
  const int wave = tid >> 6;     // 0..7
  const int wr = wave >> 2;      // 0..1 : 128-row half
  const int wc = wave & 3;       // 0..3 : 64-col quarter
  const int row0 = blockIdx.x * 256;  // batch rows
  const int col0 = blockIdx.y * 256;  // output features

  // staging map: one gload16 per array per thread per K-tile.
  // row = tid>>1 (0..255), 16B slot = (tid&1) ^ ((row>>2)&1)  (swizzle inverse)
  const int srow = tid >> 1;
  const int scol = ((tid & 1) ^ ((srow >> 2) & 1)) * 8;  // elem offset in K
  const size_t abase = (size_t)(row0 + srow) * NFEAT + scol;
  const size_t bbase = (size_t)(col0 + srow) * NFEAT + scol;
  const int dst = tid * 8;  // element offset within each 4096-elem array

  f32x16 acc[4][2] = {};

  auto STAGE = [&](int p, int k0) {
    bf16* base = smem + p * 16384;
    gload16(base + dst,         Ah + abase + k0);
    gload16(base + 4096 + dst,  Al + abase + k0);
    gload16(base + 8192 + dst,  Bh + bbase + k0);
    gload16(base + 12288 + dst, Bl + bbase + k0);
  };

  const int l31 = lane & 31;
  const int kh16 = (lane >> 5) * 16;  // byte offset of k-half (8 elems)

  STAGE(0, 0);
  int p = 0;
  for (int t = 0; t < 64; ++t) {
    if (t < 63) {
      STAGE(p ^ 1, (t + 1) * 16);
      asm volatile("s_waitcnt vmcnt(4)" ::: "memory");
    } else {
      asm volatile("s_waitcnt vmcnt(0)" ::: "memory");
    }
    __builtin_amdgcn_s_barrier();

    const char* pAh = (const char*)(smem + p * 16384);
    const char* pAl = pAh + 8192;
    const char* pBh = pAh + 16384;
    const char* pBl = pAh + 24576;

    bf16x8 fah[4], fal[4], fbh[2], fbl[2];
#pragma unroll
    for (int m = 0; m < 4; ++m) {
      const int ar = wr * 128 + m * 32 + l31;
      const int off = ar * 32 + (kh16 ^ (((ar >> 2) & 1) << 4));
      fah[m] = *(const bf16x8*)(pAh + off);
      fal[m] = *(const bf16x8*)(pAl + off);
    }
#pragma unroll
    for (int n = 0; n < 2; ++n) {
      const int br = wc * 64 + n * 32 + l31;
      const int off = br * 32 + (kh16 ^ (((br >> 2) & 1) << 4));
      fbh[n] = *(const bf16x8*)(pBh + off);
      fbl[n] = *(const bf16x8*)(pBl + off);
    }

    __builtin_amdgcn_s_setprio(1);
#pragma unroll
    for (int m = 0; m < 4; ++m)
#pragma unroll
      for (int n = 0; n < 2; ++n) {
        acc[m][n] = __builtin_amdgcn_mfma_f32_32x32x16_bf16(fah[m], fbh[n], acc[m][n], 0, 0, 0);
        acc[m][n] = __builtin_amdgcn_mfma_f32_32x32x16_bf16(fah[m], fbl[n], acc[m][n], 0, 0, 0);
        acc[m][n] = __builtin_amdgcn_mfma_f32_32x32x16_bf16(fal[m], fbh[n], acc[m][n], 0, 0, 0);
      }
    __builtin_amdgcn_s_setprio(0);

    asm volatile("s_waitcnt lgkmcnt(0)" ::: "memory");
    __builtin_amdgcn_s_barrier();
    p ^= 1;
  }

  // epilogue: 32x32 C/D layout: col = lane&31, row = (r&3)+8*(r>>2)+4*(lane>>5)
  const int ocol0 = col0 + wc * 64 + l31;
  const int rb = (lane >> 5) << 2;
#pragma unroll
  for (int m = 0; m < 4; ++m)
#pragma unroll
    for (int n = 0; n < 2; ++n)
#pragma unroll
      for (int r = 0; r < 16; ++r) {
        const int grow = row0 + wr * 128 + m * 32 + (r & 3) + ((r >> 2) << 3) + rb;
        const int gcol = ocol0 + n * 32;
        const size_t off = (size_t)grow * NFEAT + (size_t)gcol;
        const float v = acc[m][n][r];
        if (MODE & 1) Yf[off] = v;
        if (MODE & 2) {
          bf16 hb = __float2bfloat16(v);
          Yh[off] = hb;
          Yl[off] = __float2bfloat16(v - __bfloat162float(hb));
        }
      }
}

// ---------------------------------------------------------------------------
// launch
// ---------------------------------------------------------------------------
extern "C" void kernel_launch(void* const* d_in, const int* in_sizes, int n_in,
                              void* d_out, int out_size, void* d_ws, size_t ws_size,
                              hipStream_t stream) {
  (void)in_sizes; (void)n_in; (void)out_size; (void)ws_size;
  const float* x  = (const float*)d_in[0];
  const float* er = (const float*)d_in[1];
  const float* ed = (const float*)d_in[2];
  const float* dr = (const float*)d_in[3];
  const float* dd = (const float*)d_in[4];

  float* O0 = (float*)d_out;                       // bottleneck (fp32, 64 MB)
  float* O1 = O0 + (size_t)BATCH * NFEAT;          // out (fp32, 64 MB)

  // d_ws layout: Lh (16MB) | Ll (16MB) | ab (32KB) | Ph (32MB) | Pl (32MB)
  bf16* Lh = (bf16*)d_ws;
  bf16* Ll = Lh + ((size_t)8 << 20);
  float* ab = (float*)(Ll + ((size_t)8 << 20));
  bf16* Ph = (bf16*)(ab + 8 * 1024);
  bf16* Pl = Ph + (size_t)BATCH * NFEAT;
  // Tpref (64KB) at start of d_out: consumed by build, overwritten by layer 4.
  float* Tpref = O0;
  // d_out second half doubles as bf16 hi/lo ping buffer until layer 8 overwrites it
  bf16* Qh = (bf16*)O1;
  bf16* Ql = Qh + (size_t)BATCH * NFEAT;

  prep_kernel<<<8, 64, 0, stream>>>(er, ed, dr, dd, ab);
  prep2_kernel<<<8, 256, 0, stream>>>(er, ed, dr, dd, ab, Tpref);
  build_kernel<<<dim3(1024, 8), 256, 0, stream>>>(er, ed, dr, dd, ab, Tpref, Lh, Ll);
  split_kernel<<<4096, 256, 0, stream>>>(x, Qh, Ql);

  const dim3 g(64, 4);
  const size_t LM = (size_t)1 << 20;
  // encoder
  gemm3_kernel<2><<<g, 512, 0, stream>>>(Qh, Ql, Lh + 0 * LM, Ll + 0 * LM, nullptr, Ph, Pl);
  gemm3_kernel<2><<<g, 512, 0, stream>>>(Ph, Pl, Lh + 1 * LM, Ll + 1 * LM, nullptr, Qh, Ql);
  gemm3_kernel<2><<<g, 512, 0, stream>>>(Qh, Ql, Lh + 2 * LM, Ll + 2 * LM, nullptr, Ph, Pl);
  gemm3_kernel<3><<<g, 512, 0, stream>>>(Ph, Pl, Lh + 3 * LM, Ll + 3 * LM, O0, Qh, Ql);
  // decoder
  gemm3_kernel<2><<<g, 512, 0, stream>>>(Qh, Ql, Lh + 4 * LM, Ll + 4 * LM, nullptr, Ph, Pl);
  gemm3_kernel<2><<<g, 512, 0, stream>>>(Ph, Pl, Lh + 5 * LM, Ll + 5 * LM, nullptr, Qh, Ql);
  gemm3_kernel<2><<<g, 512, 0, stream>>>(Qh, Ql, Lh + 6 * LM, Ll + 6 * LM, nullptr, Ph, Pl);
  gemm3_kernel<1><<<g, 512, 0, stream>>>(Ph, Pl, Lh + 7 * LM, Ll + 7 * LM, O1, nullptr, nullptr);
}

// Round 6
// 918.645 us; speedup vs baseline: 1.0285x; 1.0285x over previous
//
#include <hip/hip_runtime.h>
#include <hip/hip_bf16.h>
#include <cstdint>
#include <cstddef>

#define H 512
#define NFEAT 1024
#define BATCH 16384

using bf16 = __hip_bfloat16;
using bf16x8 = __attribute__((ext_vector_type(8))) __bf16;
using f32x4 = __attribute__((ext_vector_type(4))) float;
using f32x16 = __attribute__((ext_vector_type(16))) float;

// ---------------------------------------------------------------------------
// async global -> LDS, 16 bytes per lane
// ---------------------------------------------------------------------------
__device__ __forceinline__ void gload16(void* lds, const void* g) {
  __builtin_amdgcn_global_load_lds(
      (__attribute__((address_space(1))) void*)g,
      (__attribute__((address_space(3))) void*)lds,
      16, 0, 0);
}

// ---------------------------------------------------------------------------
// prep: per matrix, compute a[], b[] for core = diag(d) + a*1^T + b*u^T
// Closed-form Cayley (rank-2 Woodbury), verified R0-R5.
// ---------------------------------------------------------------------------
__global__ void prep_kernel(const float* __restrict__ er, const float* __restrict__ ed,
                            const float* __restrict__ dr, const float* __restrict__ dd,
                            float* __restrict__ ab) {
  const int mat = blockIdx.x;          // 0..7
  const int lane = threadIdx.x;        // 0..63
  const float* u = (mat < 4) ? (er + mat * H) : (dr + (mat - 4) * H);
  const float* d = (mat < 4) ? (ed + mat * H) : (dd + (mat - 4) * H);

  double s = 0.0, q = 0.0;
  for (int k = 0; k < 8; ++k) {
    double v = (double)u[lane + 64 * k];
    s += v;
    q += v * v;
  }
  for (int off = 32; off; off >>= 1) {
    s += __shfl_down(s, off);
    q += __shfl_down(q, off);
  }
  s = __shfl(s, 0);
  q = __shfl(q, 0);

  const double det = 1.0 - s * s + (double)H * q;
  const double cuv = 2.0 * (1.0 + s) / det;
  const double cuu = -2.0 * (double)H / det;
  const double cvv = -2.0 * q / det;
  const double cvu = -2.0 * (1.0 - s) / det;

  float* a = ab + mat * 1024;
  float* b = a + H;
  for (int k = 0; k < 8; ++k) {
    int idx = lane + 64 * k;
    double ui = (double)u[idx], di = (double)d[idx];
    a[idx] = (float)(di * (cuv * ui + cvv));
    b[idx] = (float)(di * (cuu * ui + cvu));
  }
}

// ---------------------------------------------------------------------------
// prep2: stride-4-residue inclusive prefix tables over a, a_rev, d, d_rev.
// ---------------------------------------------------------------------------
__global__ __launch_bounds__(256) void prep2_kernel(
    const float* __restrict__ er, const float* __restrict__ ed,
    const float* __restrict__ dr, const float* __restrict__ dd,
    const float* __restrict__ ab, float* __restrict__ Tpref) {
  __shared__ float buf[4][512];
  __shared__ float tmp[4][512];
  const int mat = blockIdx.x;
  const float* d = (mat < 4) ? (ed + mat * H) : (dd + (mat - 4) * H);
  const float* a = ab + mat * 1024;
  const int t = threadIdx.x;
  for (int m = t; m < 512; m += 256) {
    buf[0][m] = a[m];
    buf[1][m] = a[511 - m];
    buf[2][m] = d[m];
    buf[3][m] = d[511 - m];
  }
  __syncthreads();
  for (int s = 4; s <= 256; s <<= 1) {
    for (int m = t; m < 512; m += 256)
#pragma unroll
      for (int q = 0; q < 4; ++q) tmp[q][m] = (m >= s) ? buf[q][m - s] : 0.f;
    __syncthreads();
    for (int m = t; m < 512; m += 256)
#pragma unroll
      for (int q = 0; q < 4; ++q) buf[q][m] += tmp[q][m];
    __syncthreads();
  }
  float* tp = Tpref + mat * 2048;
  for (int m = t; m < 512; m += 256) {
    tp[m] = buf[0][m];
    tp[512 + m] = buf[1][m];
    tp[1024 + m] = buf[2][m];
    tp[1536 + m] = buf[3][m];
  }
}

// ---------------------------------------------------------------------------
// build v3 (unchanged from R2): prefix tables + quad b*u loop.
// ---------------------------------------------------------------------------
__global__ __launch_bounds__(256) void build_kernel(
    const float* __restrict__ er, const float* __restrict__ ed,
    const float* __restrict__ dr, const float* __restrict__ dd,
    const float* __restrict__ ab, const float* __restrict__ Tpref,
    bf16* __restrict__ Lh, bf16* __restrict__ Ll) {
  __shared__ __align__(16) float arr4[4][520];
  __shared__ __align__(16) float4 up[132];
  __shared__ float pa[512], parev[512], pd[512], pdrev[512], sdl[512];

  const int i = blockIdx.x;
  const int mat = blockIdx.y;
  const float* u = (mat < 4) ? (er + mat * H) : (dr + (mat - 4) * H);
  const float* d = (mat < 4) ? (ed + mat * H) : (dd + (mat - 4) * H);
  const float* a = ab + mat * 1024;
  const float* b = a + H;
  const float* tp = Tpref + mat * 2048;
  const int t = threadIdx.x;

  for (int m = t; m < 520; m += 256) {
    arr4[0][m] = (m < 512) ? u[m] : 0.f;
    arr4[1][m] = (m >= 1 && m <= 512) ? b[m - 1] : 0.f;
    arr4[2][m] = (m >= 2 && m <= 513) ? u[513 - m] : 0.f;
    arr4[3][m] = (m >= 3 && m <= 514) ? b[514 - m] : 0.f;
  }
  for (int m = t; m < 512; m += 256) {
    pa[m] = tp[m];
    parev[m] = tp[512 + m];
    pd[m] = tp[1024 + m];
    pdrev[m] = tp[1536 + m];
    sdl[m] = d[m];
  }
  if (t < 132) {
    const int k4 = 4 * t;
    float4 v;
    int p0 = i - k4;
    v.x = (p0 >= 0 && p0 < 512) ? b[p0] : 0.f;
    int p1 = i - k4 - 1;
    v.y = (p1 >= 0 && p1 < 512) ? u[511 - p1] : 0.f;
    int p2 = i - k4 - 2;
    v.z = (p2 >= 0 && p2 < 512) ? b[511 - p2] : 0.f;
    int p3 = i - k4 - 3;
    v.w = (p3 >= 0 && p3 < 512) ? u[p3] : 0.f;
    up[t] = v;
  }
  __syncthreads();

  const float* upf = (const float*)up;
  const int j0 = t * 4;

  int lo_[4], hi_[4];
#pragma unroll
  for (int c = 0; c < 4; ++c) {
    const int jc = j0 + c;
    lo_[c] = max(0, max(i, jc) - 511);
    hi_[c] = min(512, min(i, jc));
  }
  const int CL = lo_[3];
  const int CH = hi_[0];

  float acc[4] = {0.f, 0.f, 0.f, 0.f};

#pragma unroll
  for (int c = 0; c < 4; ++c) {
    const int jc = j0 + c;
    const int lo = lo_[c], hi = hi_[c];
    if (lo > hi) continue;
    float v = 0.f;
    {
      int o1 = lo + ((0 - lo) & 3), o2 = hi - ((hi - 0) & 3);
      if (o1 <= o2) { int mx = i - o1, mn = i - o2; v += pa[mx] - (mn >= 4 ? pa[mn - 4] : 0.f); }
    }
    {
      int o1 = lo + ((1 - lo) & 3), o2 = hi - ((hi - 1) & 3);
      if (o1 <= o2) { int mx = jc - o1, mn = jc - o2; v += pa[mx] - (mn >= 4 ? pa[mn - 4] : 0.f); }
    }
    {
      int o1 = lo + ((2 - lo) & 3), o2 = hi - ((hi - 2) & 3);
      if (o1 <= o2) { int mx = i - o1, mn = i - o2; v += parev[mx] - (mn >= 4 ? parev[mn - 4] : 0.f); }
    }
    {
      int o1 = lo + ((3 - lo) & 3), o2 = hi - ((hi - 3) & 3);
      if (o1 <= o2) { int mx = jc - o1, mn = jc - o2; v += parev[mx] - (mn >= 4 ? parev[mn - 4] : 0.f); }
    }
    if (i == jc) {
      {
        int o1 = lo + ((0 - lo) & 3), o2 = hi - ((hi - 0) & 3);
        if (o1 <= o2) { int mx = i - o1, mn = i - o2; v += pd[mx] - (mn >= 4 ? pd[mn - 4] : 0.f); }
      }
      {
        int o1 = lo + ((2 - lo) & 3), o2 = hi - ((hi - 2) & 3);
        if (o1 <= o2) { int mx = i - o1, mn = i - o2; v += pdrev[mx] - (mn >= 4 ? pdrev[mn - 4] : 0.f); }
      }
    }
    const int m2 = i + jc - 511;
    if (m2 >= 0 && !(m2 & 1)) {
      const int os = m2 >> 1;
      if (os >= lo && os <= hi) {
        const int r = os & 3;
        if (r == 1) v += sdl[jc - os];
        else if (r == 3) v += sdl[511 - (jc - os)];
      }
    }
    acc[c] = v;
  }

  if (CL > CH) {
#pragma unroll
    for (int c = 0; c < 4; ++c) {
      const int jc = j0 + c;
      for (int o = lo_[c]; o <= hi_[c]; ++o) {
        const int r = o & 3;
        acc[c] += upf[o] * arr4[r][jc - o + r];
      }
    }
  } else {
#pragma unroll
    for (int c = 0; c < 4; ++c) {
      const int jc = j0 + c;
      const int he = min(hi_[c], CL - 1);
      for (int o = lo_[c]; o <= he; ++o) {
        const int r = o & 3;
        acc[c] += upf[o] * arr4[r][jc - o + r];
      }
      const int ls = max(lo_[c], CH + 1);
      for (int o = ls; o <= hi_[c]; ++o) {
        const int r = o & 3;
        acc[c] += upf[o] * arr4[r][jc - o + r];
      }
    }
    const int QL = (CL + 3) & ~3;
    for (int o = CL; o < QL && o <= CH; ++o) {
      const int r = o & 3;
      const float uvv = upf[o];
      const float4 wv = *(const float4*)&arr4[r][j0 - o + r];
      acc[0] += uvv * wv.x; acc[1] += uvv * wv.y;
      acc[2] += uvv * wv.z; acc[3] += uvv * wv.w;
    }
    int ob = QL;
    for (; ob + 3 <= CH; ob += 4) {
      const float4 uv = up[ob >> 2];
      const int x = j0 - ob;
      const float4 w0 = *(const float4*)&arr4[0][x];
      const float4 w1 = *(const float4*)&arr4[1][x];
      const float4 w2 = *(const float4*)&arr4[2][x];
      const float4 w3 = *(const float4*)&arr4[3][x];
      acc[0] += uv.x * w0.x + uv.y * w1.x + uv.z * w2.x + uv.w * w3.x;
      acc[1] += uv.x * w0.y + uv.y * w1.y + uv.z * w2.y + uv.w * w3.y;
      acc[2] += uv.x * w0.z + uv.y * w1.z + uv.z * w2.z + uv.w * w3.z;
      acc[3] += uv.x * w0.w + uv.y * w1.w + uv.z * w2.w + uv.w * w3.w;
    }
    for (int o = ob; o <= CH; ++o) {
      const int r = o & 3;
      const float uvv = upf[o];
      const float4 wv = *(const float4*)&arr4[r][j0 - o + r];
      acc[0] += uvv * wv.x; acc[1] += uvv * wv.y;
      acc[2] += uvv * wv.z; acc[3] += uvv * wv.w;
    }
  }

  const size_t off = ((size_t)mat << 20) + ((size_t)i << 10) + (size_t)j0;
  union { bf16 v[4]; ushort4 s; } Hu, Lu;
#pragma unroll
  for (int c = 0; c < 4; ++c) {
    const bf16 hb = __float2bfloat16(acc[c]);
    Hu.v[c] = hb;
    Lu.v[c] = __float2bfloat16(acc[c] - __bfloat162float(hb));
  }
  *(ushort4*)(Lh + off) = Hu.s;
  *(ushort4*)(Ll + off) = Lu.s;
}

// ---------------------------------------------------------------------------
// split fp32 -> (hi, lo) bf16
// ---------------------------------------------------------------------------
__global__ void split_kernel(const float* __restrict__ x, bf16* __restrict__ h,
                             bf16* __restrict__ l) {
  const int n4 = BATCH * NFEAT / 4;
  int idx = blockIdx.x * blockDim.x + threadIdx.x;
  int stride = gridDim.x * blockDim.x;
  for (int i = idx; i < n4; i += stride) {
    float4 v = ((const float4*)x)[i];
    float vv[4] = {v.x, v.y, v.z, v.w};
    union { bf16 b[4]; short4 s; } Hu, Lu;
#pragma unroll
    for (int c = 0; c < 4; ++c) {
      bf16 hb = __float2bfloat16(vv[c]);
      Hu.b[c] = hb;
      Lu.b[c] = __float2bfloat16(vv[c] - __bfloat162float(hb));
    }
    ((short4*)h)[i] = Hu.s;
    ((short4*)l)[i] = Lu.s;
  }
}

// ---------------------------------------------------------------------------
// split-bf16 GEMM v4:  Y[r][c] = sum_k S[r][k] * L[c][k]  (Y = S @ L^T)
// acc += Ah*Bh + Ah*Bl + Al*Bh (fp32 accum).
// 256x256 tile, BK=32, 8 waves (2Mx4N, wave 128x64), mfma_f32_32x32x16.
// 4-phase interleaved schedule per K-tile (T3+T4+T5):
//   phase = { 2 staging gloads (tile t+1) ; 4-8 ds_read_b128 ;
//             s_barrier ; setprio(1) ; 12 MFMA ; setprio(0) ; s_barrier }
// vmcnt(0) once per tile (loads issued >=3 phases earlier -> ~0 wait).
// Raw s_barrier only (no __syncthreads -> no per-phase vmcnt drain).
// LDS: dbuf x 4 arrays x [256][32] bf16 = 128 KiB. Granule swizzle:
//   phys_g = g ^ ((row>>1)&3) applied on stage source and frag read.
// MODE bit0: write fp32 Yf; bit1: write split (Yh, Yl)
// ---------------------------------------------------------------------------
template <int MODE>
__global__ __launch_bounds__(512, 2) void gemm3_kernel(
    const bf16* __restrict__ Ah, const bf16* __restrict__ Al,
    const bf16* __restrict__ Bh, const bf16* __restrict__ Bl,
    float* __restrict__ Yf, bf16* __restrict__ Yh, bf16* __restrict__ Yl) {
  __shared__ __align__(16) bf16 smem[2 * 4 * 8192];  // 128 KiB

  const int tid = threadIdx.x;   // 0..511
  const int lane = tid & 63;
  const int wave = tid >> 6;     // 0..7
  const int wr = wave >> 2;      // 0..1 : 128-row half
  const int wc = wave & 3;       // 0..3 : 64-col quarter

  // XCD-chunked bijective block swizzle (grid 64x4 = 256 = 8*32)
  const int pdisp = blockIdx.x + (blockIdx.y << 6);
  const int lblk = ((pdisp & 7) << 5) + (pdisp >> 3);
  const int row0 = (lblk & 63) * 256;
  const int col0 = (lblk >> 6) * 256;

  // staging: per K-tile, per array: 2 gload16/thread (rows q*128 + tid>>2)
  const int gsrc = (tid & 3) ^ ((tid >> 3) & 3);   // inverse-swizzled src granule
  const int dst = tid * 8;                          // linear dest elems (+q*4096)
  const size_t abase = (size_t)(row0 + (tid >> 2)) * NFEAT + gsrc * 8;
  const size_t bbase = (size_t)(col0 + (tid >> 2)) * NFEAT + gsrc * 8;

  auto STAGE2 = [&](int nb, int arr, const bf16* __restrict__ src, size_t base, int k0) {
    bf16* d = smem + nb * 32768 + arr * 8192 + dst;
    gload16(d, src + base + k0);
    gload16(d + 4096, src + base + 131072 + k0);   // +128 rows
  };

  // frag-read byte offsets: row r, k-step ks, k-half hb
  const int l31 = lane & 31;
  const int hb = lane >> 5;
  int aoffB[4][2], boffB[2][2];
#pragma unroll
  for (int m = 0; m < 4; ++m) {
    const int r = wr * 128 + m * 32 + l31;
#pragma unroll
    for (int ks = 0; ks < 2; ++ks)
      aoffB[m][ks] = r * 64 + ((((ks << 1) | hb) ^ ((r >> 1) & 3)) << 4);
  }
#pragma unroll
  for (int n = 0; n < 2; ++n) {
    const int r = wc * 64 + n * 32 + l31;
#pragma unroll
    for (int ks = 0; ks < 2; ++ks)
      boffB[n][ks] = r * 64 + ((((ks << 1) | hb) ^ ((r >> 1) & 3)) << 4);
  }

  auto LD = [](const char* base, int off) { return *(const bf16x8*)(base + off); };
  auto TRIPLE = [](f32x16& ac, bf16x8 ah, bf16x8 al, bf16x8 bh, bf16x8 bl) {
    ac = __builtin_amdgcn_mfma_f32_32x32x16_bf16(ah, bh, ac, 0, 0, 0);
    ac = __builtin_amdgcn_mfma_f32_32x32x16_bf16(ah, bl, ac, 0, 0, 0);
    ac = __builtin_amdgcn_mfma_f32_32x32x16_bf16(al, bh, ac, 0, 0, 0);
  };

  f32x16 acc[4][2] = {};

  // prologue: stage tile 0 into buffer 0
  STAGE2(0, 0, Ah, abase, 0);
  STAGE2(0, 1, Al, abase, 0);
  STAGE2(0, 2, Bh, bbase, 0);
  STAGE2(0, 3, Bl, bbase, 0);
  asm volatile("s_waitcnt vmcnt(0)" ::: "memory");
  __builtin_amdgcn_s_barrier();

  for (int t = 0; t < 32; ++t) {
    const int buf = t & 1;
    const int nb = buf ^ 1;
    const int k1 = (t + 1) * 32;
    const char* pAh = (const char*)(smem + buf * 32768);
    const char* pAl = pAh + 16384;
    const char* pBh = pAh + 32768;
    const char* pBl = pAh + 49152;
    const bool pf = (t < 31);

    bf16x8 fah[2], fal[2], fbh[2], fbl[2];

    // ---- Phase 0: ks0, m0/m1 ----
    if (pf) STAGE2(nb, 0, Ah, abase, k1);
    fah[0] = LD(pAh, aoffB[0][0]); fal[0] = LD(pAl, aoffB[0][0]);
    fah[1] = LD(pAh, aoffB[1][0]); fal[1] = LD(pAl, aoffB[1][0]);
    fbh[0] = LD(pBh, boffB[0][0]); fbl[0] = LD(pBl, boffB[0][0]);
    fbh[1] = LD(pBh, boffB[1][0]); fbl[1] = LD(pBl, boffB[1][0]);
    __builtin_amdgcn_s_barrier();
    __builtin_amdgcn_s_setprio(1);
    TRIPLE(acc[0][0], fah[0], fal[0], fbh[0], fbl[0]);
    TRIPLE(acc[0][1], fah[0], fal[0], fbh[1], fbl[1]);
    TRIPLE(acc[1][0], fah[1], fal[1], fbh[0], fbl[0]);
    TRIPLE(acc[1][1], fah[1], fal[1], fbh[1], fbl[1]);
    __builtin_amdgcn_s_setprio(0);
    __builtin_amdgcn_s_barrier();

    // ---- Phase 1: ks0, m2/m3 ----
    if (pf) STAGE2(nb, 1, Al, abase, k1);
    fah[0] = LD(pAh, aoffB[2][0]); fal[0] = LD(pAl, aoffB[2][0]);
    fah[1] = LD(pAh, aoffB[3][0]); fal[1] = LD(pAl, aoffB[3][0]);
    __builtin_amdgcn_s_barrier();
    __builtin_amdgcn_s_setprio(1);
    TRIPLE(acc[2][0], fah[0], fal[0], fbh[0], fbl[0]);
    TRIPLE(acc[2][1], fah[0], fal[0], fbh[1], fbl[1]);
    TRIPLE(acc[3][0], fah[1], fal[1], fbh[0], fbl[0]);
    TRIPLE(acc[3][1], fah[1], fal[1], fbh[1], fbl[1]);
    __builtin_amdgcn_s_setprio(0);
    __builtin_amdgcn_s_barrier();

    // ---- Phase 2: ks1, m0/m1 ----
    if (pf) STAGE2(nb, 2, Bh, bbase, k1);
    fah[0] = LD(pAh, aoffB[0][1]); fal[0] = LD(pAl, aoffB[0][1]);
    fah[1] = LD(pAh, aoffB[1][1]); fal[1] = LD(pAl, aoffB[1][1]);
    fbh[0] = LD(pBh, boffB[0][1]); fbl[0] = LD(pBl, boffB[0][1]);
    fbh[1] = LD(pBh, boffB[1][1]); fbl[1] = LD(pBl, boffB[1][1]);
    __builtin_amdgcn_s_barrier();
    __builtin_amdgcn_s_setprio(1);
    TRIPLE(acc[0][0], fah[0], fal[0], fbh[0], fbl[0]);
    TRIPLE(acc[0][1], fah[0], fal[0], fbh[1], fbl[1]);
    TRIPLE(acc[1][0], fah[1], fal[1], fbh[0], fbl[0]);
    TRIPLE(acc[1][1], fah[1], fal[1], fbh[1], fbl[1]);
    __builtin_amdgcn_s_setprio(0);
    __builtin_amdgcn_s_barrier();

    // ---- Phase 3: ks1, m2/m3 ----
    if (pf) STAGE2(nb, 3, Bl, bbase, k1);
    fah[0] = LD(pAh, aoffB[2][1]); fal[0] = LD(pAl, aoffB[2][1]);
    fah[1] = LD(pAh, aoffB[3][1]); fal[1] = LD(pAl, aoffB[3][1]);
    __builtin_amdgcn_s_barrier();
    __builtin_amdgcn_s_setprio(1);
    TRIPLE(acc[2][0], fah[0], fal[0], fbh[0], fbl[0]);
    TRIPLE(acc[2][1], fah[0], fal[0], fbh[1], fbl[1]);
    TRIPLE(acc[3][0], fah[1], fal[1], fbh[0], fbl[0]);
    TRIPLE(acc[3][1], fah[1], fal[1], fbh[1], fbl[1]);
    __builtin_amdgcn_s_setprio(0);
    // tile-end: ensure next buffer fully staged before swap
    asm volatile("s_waitcnt vmcnt(0)" ::: "memory");
    __builtin_amdgcn_s_barrier();
  }

  // epilogue: 32x32 C/D layout: col = lane&31, row = (r&3)+8*(r>>2)+4*(lane>>5)
  const int ocol0 = col0 + wc * 64 + l31;
  const int rb = (lane >> 5) << 2;
#pragma unroll
  for (int m = 0; m < 4; ++m)
#pragma unroll
    for (int n = 0; n < 2; ++n)
#pragma unroll
      for (int r = 0; r < 16; ++r) {
        const int grow = row0 + wr * 128 + m * 32 + (r & 3) + ((r >> 2) << 3) + rb;
        const int gcol = ocol0 + n * 32;
        const size_t off = (size_t)grow * NFEAT + (size_t)gcol;
        const float v = acc[m][n][r];
        if (MODE & 1) Yf[off] = v;
        if (MODE & 2) {
          bf16 hbv = __float2bfloat16(v);
          Yh[off] = hbv;
          Yl[off] = __float2bfloat16(v - __bfloat162float(hbv));
        }
      }
}

// ---------------------------------------------------------------------------
// launch
// ---------------------------------------------------------------------------
extern "C" void kernel_launch(void* const* d_in, const int* in_sizes, int n_in,
                              void* d_out, int out_size, void* d_ws, size_t ws_size,
                              hipStream_t stream) {
  (void)in_sizes; (void)n_in; (void)out_size; (void)ws_size;
  const float* x  = (const float*)d_in[0];
  const float* er = (const float*)d_in[1];
  const float* ed = (const float*)d_in[2];
  const float* dr = (const float*)d_in[3];
  const float* dd = (const float*)d_in[4];

  float* O0 = (float*)d_out;                       // bottleneck (fp32, 64 MB)
  float* O1 = O0 + (size_t)BATCH * NFEAT;          // out (fp32, 64 MB)

  // d_ws layout: Lh (16MB) | Ll (16MB) | ab (32KB) | Ph (32MB) | Pl (32MB)
  bf16* Lh = (bf16*)d_ws;
  bf16* Ll = Lh + ((size_t)8 << 20);
  float* ab = (float*)(Ll + ((size_t)8 << 20));
  bf16* Ph = (bf16*)(ab + 8 * 1024);
  bf16* Pl = Ph + (size_t)BATCH * NFEAT;
  // Tpref (64KB) at start of d_out: consumed by build, overwritten by layer 4.
  float* Tpref = O0;
  // d_out second half doubles as bf16 hi/lo ping buffer until layer 8 overwrites it
  bf16* Qh = (bf16*)O1;
  bf16* Ql = Qh + (size_t)BATCH * NFEAT;

  prep_kernel<<<8, 64, 0, stream>>>(er, ed, dr, dd, ab);
  prep2_kernel<<<8, 256, 0, stream>>>(er, ed, dr, dd, ab, Tpref);
  build_kernel<<<dim3(1024, 8), 256, 0, stream>>>(er, ed, dr, dd, ab, Tpref, Lh, Ll);
  split_kernel<<<4096, 256, 0, stream>>>(x, Qh, Ql);

  const dim3 g(64, 4);
  const size_t LM = (size_t)1 << 20;
  // encoder
  gemm3_kernel<2><<<g, 512, 0, stream>>>(Qh, Ql, Lh + 0 * LM, Ll + 0 * LM, nullptr, Ph, Pl);
  gemm3_kernel<2><<<g, 512, 0, stream>>>(Ph, Pl, Lh + 1 * LM, Ll + 1 * LM, nullptr, Qh, Ql);
  gemm3_kernel<2><<<g, 512, 0, stream>>>(Qh, Ql, Lh + 2 * LM, Ll + 2 * LM, nullptr, Ph, Pl);
  gemm3_kernel<3><<<g, 512, 0, stream>>>(Ph, Pl, Lh + 3 * LM, Ll + 3 * LM, O0, Qh, Ql);
  // decoder
  gemm3_kernel<2><<<g, 512, 0, stream>>>(Qh, Ql, Lh + 4 * LM, Ll + 4 * LM, nullptr, Ph, Pl);
  gemm3_kernel<2><<<g, 512, 0, stream>>>(Ph, Pl, Lh + 5 * LM, Ll + 5 * LM, nullptr, Qh, Ql);
  gemm3_kernel<2><<<g, 512, 0, stream>>>(Qh, Ql, Lh + 6 * LM, Ll + 6 * LM, nullptr, Ph, Pl);
  gemm3_kernel<1><<<g, 512, 0, stream>>>(Ph, Pl, Lh + 7 * LM, Ll + 7 * LM, O1, nullptr, nullptr);
}